// Round 1
// baseline (501.142 us; speedup 1.0000x reference)
//
#include <hip/hip_runtime.h>
#include <hip/hip_bf16.h>

typedef unsigned short u16;
typedef unsigned int u32;

using bf16x8 = __attribute__((ext_vector_type(8))) short;
using f32x4  = __attribute__((ext_vector_type(4))) float;

static constexpr int TOK  = 8192;   // BS*L
static constexpr int SEQ  = 2048;
static constexpr int DM   = 1024;
static constexpr int FF   = 4096;
static constexpr int NE   = 8;
static constexpr int MAXT = 72;     // max M-tiles: 8192/128 + 8 remainders

// ---- workspace layout (bytes) ----
static constexpr size_t O_LOGITS = 0;                                  // 8192*8*4
static constexpr size_t O_M      = 262144;                            // 32 f32
static constexpr size_t O_Z      = O_M + 128;                         // 32 f32
static constexpr size_t O_CNT    = O_Z + 128;                         // 8 u32
static constexpr size_t O_CUR    = O_CNT + 64;                        // 8 u32
static constexpr size_t O_OFF    = O_CUR + 64;                        // 9 i32
static constexpr size_t O_DESC   = 263168;                            // 72 * int4
static constexpr size_t O_PERM   = 266240;                            // 8192 i32
static constexpr size_t O_IDX    = 299008;                            // 8192 i32
static constexpr size_t O_XG     = 524288;                            // 16 MB bf16
static constexpr size_t O_W1T    = O_XG  + (size_t)TOK*DM*2;          // 64 MB bf16 [e][f][d]
static constexpr size_t O_W2T    = O_W1T + (size_t)NE*DM*FF*2;        // 64 MB bf16 [e][d][f]
static constexpr size_t O_H      = O_W2T + (size_t)NE*DM*FF*2;        // 64 MB bf16 [pos][f]
// total ~218.6 MB

__device__ __forceinline__ u16 f2bf(float f){
  __hip_bfloat16 h = __float2bfloat16(f);
  return *reinterpret_cast<u16*>(&h);
}

__device__ __forceinline__ void gld_lds16(const void* g, void* l){
  __builtin_amdgcn_global_load_lds((const __attribute__((address_space(1))) void*)g,
                                   (__attribute__((address_space(3))) void*)l, 16, 0, 0);
}

// ---- 1) gate logits: one wave per token, fp32, tree-reduced ----
__global__ void k_gate(const float* __restrict__ x, const float* __restrict__ gw,
                       const float* __restrict__ gb, float* __restrict__ logits){
  __shared__ float sgw[DM*NE];
  for (int i = threadIdx.x; i < DM*NE; i += 256) sgw[i] = gw[i];
  __syncthreads();
  int wave = threadIdx.x >> 6, lane = threadIdx.x & 63;
  int t = blockIdx.x * 4 + wave;
  const float* xr = x + (size_t)t * DM;
  float acc[NE];
#pragma unroll
  for (int e = 0; e < NE; ++e) acc[e] = 0.f;
#pragma unroll
  for (int k = 0; k < 16; ++k){
    int d = k*64 + lane;
    float xv = xr[d];
    const float* g = &sgw[d*NE];
#pragma unroll
    for (int e = 0; e < NE; ++e) acc[e] = fmaf(xv, g[e], acc[e]);
  }
#pragma unroll
  for (int off = 32; off; off >>= 1)
#pragma unroll
    for (int e = 0; e < NE; ++e) acc[e] += __shfl_xor(acc[e], off);
  if (lane == 0){
#pragma unroll
    for (int e = 0; e < NE; ++e) logits[(size_t)t*NE + e] = acc[e] + gb[e];
  }
}

// ---- 2) per (b,e): max and sum(exp) over seq ----
__global__ void k_lse(const float* __restrict__ logits, float* __restrict__ mOut,
                      float* __restrict__ zOut){
  int be = blockIdx.x;            // b*8+e
  int b = be >> 3, e = be & 7;
  const float* base = logits + ((size_t)b*SEQ)*NE + e;
  float m = -INFINITY;
  for (int l = threadIdx.x; l < SEQ; l += 256) m = fmaxf(m, base[(size_t)l*NE]);
  __shared__ float red[8];
#pragma unroll
  for (int off = 32; off; off >>= 1) m = fmaxf(m, __shfl_xor(m, off));
  if ((threadIdx.x & 63) == 0) red[threadIdx.x >> 6] = m;
  __syncthreads();
  m = fmaxf(fmaxf(red[0], red[1]), fmaxf(red[2], red[3]));
  float s = 0.f;
  for (int l = threadIdx.x; l < SEQ; l += 256) s += expf(base[(size_t)l*NE] - m);
#pragma unroll
  for (int off = 32; off; off >>= 1) s += __shfl_xor(s, off);
  if ((threadIdx.x & 63) == 0) red[4 + (threadIdx.x >> 6)] = s;
  __syncthreads();
  if (threadIdx.x == 0){ mOut[be] = m; zOut[be] = red[4]+red[5]+red[6]+red[7]; }
}

// ---- 3) route: argmax_e of softmax(dim=seq) prob, count per expert ----
__global__ void k_route(const float* __restrict__ logits, const float* __restrict__ m,
                        const float* __restrict__ z, u32* __restrict__ cnt,
                        int* __restrict__ idx){
  int t = blockIdx.x*256 + threadIdx.x;
  int b = t >> 11;
  const float* lr = logits + (size_t)t*NE;
  float best = -INFINITY; int be = 0;
#pragma unroll
  for (int e = 0; e < NE; ++e){
    float p = expf(lr[e] - m[b*NE + e]) / z[b*NE + e];
    if (p > best){ best = p; be = e; }
  }
  idx[t] = be;
  atomicAdd(&cnt[be], 1u);
}

// ---- 4) plan: prefix offsets + static tile descriptors ----
__global__ void k_plan(const u32* __restrict__ cnt, int* __restrict__ off,
                       int4* __restrict__ desc, u32* __restrict__ cur){
  if (threadIdx.x == 0){
    int offs[NE+1]; int o = 0;
    for (int e = 0; e < NE; ++e){ offs[e] = o; o += (int)cnt[e]; }
    offs[NE] = o;
    int nt = 0;
    for (int e = 0; e < NE; ++e){
      int c = (int)cnt[e];
      for (int s = 0; s < c; s += 128)
        desc[nt++] = make_int4(e, offs[e] + s, min(128, c - s), 0);
      off[e] = offs[e]; cur[e] = 0u;
    }
    off[NE] = offs[NE];
    for (int i = nt; i < MAXT; ++i) desc[i] = make_int4(-1, 0, 0, 0);
  }
}

// ---- 5) scatter token ids into expert-sorted perm ----
__global__ void k_scatter(const int* __restrict__ idx, const int* __restrict__ off,
                          u32* __restrict__ cur, int* __restrict__ perm){
  int t = blockIdx.x*256 + threadIdx.x;
  int e = idx[t];
  int pos = off[e] + (int)atomicAdd(&cur[e], 1u);
  perm[pos] = t;
}

// ---- 6) gather x rows in perm order, fp32 -> bf16 ----
__global__ void k_gather(const float* __restrict__ x, const int* __restrict__ perm,
                         u16* __restrict__ Xg){
  int p = blockIdx.x;
  int t = perm[p];
  const float4* src = (const float4*)(x + (size_t)t*DM);
  float4 v = src[threadIdx.x];
  uint2 o;
  o.x = (u32)f2bf(v.x) | ((u32)f2bf(v.y) << 16);
  o.y = (u32)f2bf(v.z) | ((u32)f2bf(v.w) << 16);
  *(uint2*)(Xg + (size_t)p*DM + threadIdx.x*4) = o;
}

// ---- 7) transpose + convert weights: in fp32 [E][R][C] -> out bf16 [E][C][R] ----
__global__ void k_trans(const float* __restrict__ in, u16* __restrict__ out,
                        int R, int C){
  __shared__ float tile[64][65];
  int e = blockIdx.z;
  int r0 = blockIdx.x*64, c0 = blockIdx.y*64;
  const float* src = in + ((size_t)e*R + r0)*C + c0;
  int lr = threadIdx.x >> 4, lc = (threadIdx.x & 15) * 4;
#pragma unroll
  for (int i = 0; i < 4; ++i){
    float4 v = *(const float4*)(src + (size_t)(lr + i*16)*C + lc);
    tile[lr + i*16][lc+0] = v.x; tile[lr + i*16][lc+1] = v.y;
    tile[lr + i*16][lc+2] = v.z; tile[lr + i*16][lc+3] = v.w;
  }
  __syncthreads();
  u16* dst = out + ((size_t)e*C + c0)*R + r0;
#pragma unroll
  for (int i = 0; i < 4; ++i){
    int oc = lr + i*16;          // output row = original column
    u16 a0 = f2bf(tile[lc+0][oc]);
    u16 a1 = f2bf(tile[lc+1][oc]);
    u16 a2 = f2bf(tile[lc+2][oc]);
    u16 a3 = f2bf(tile[lc+3][oc]);
    uint2 o; o.x = (u32)a0 | ((u32)a1 << 16); o.y = (u32)a2 | ((u32)a3 << 16);
    *(uint2*)(dst + (size_t)oc*R + lc) = o;
  }
}

// ---- 8) grouped GEMM 1: H = gelu(Xg @ W1T^T + b1), bf16 out ----
// m97 structure: 128x128 tile, BK=32, 4 waves (2x2), global_load_lds x16, dbuf LDS.
__global__ __launch_bounds__(256) void k_ffn1(const u16* __restrict__ Xg,
    const u16* __restrict__ W1T, const float* __restrict__ b1,
    u16* __restrict__ H, const int4* __restrict__ desc){
  int4 dd = desc[blockIdx.x];
  int e = dd.x; if (e < 0) return;
  int m0 = dd.y, valid = dd.z;
  int n0 = blockIdx.y * 128;
  __shared__ __align__(16) u16 lA[2][128*32];
  __shared__ __align__(16) u16 lB[2][128*32];
  int tid = threadIdx.x, lane = tid & 63, wave = tid >> 6;
  int wr = wave >> 1, wc = wave & 1;
  const u16* Bsrc = W1T + ((size_t)e*FF + n0)*DM;   // rows = f (n), k-contig
  f32x4 acc[4][4] = {};

  auto stage = [&](int buf, int kt){
    int k0 = kt * 32;
#pragma unroll
    for (int i = 0; i < 2; ++i){
      int qbase = wave*512 + i*2048;               // wave-uniform LDS elem base
      int qe = qbase + lane*8;
      int row = qe >> 5, col = qe & 31;
      int rowg = m0 + row; if (rowg > TOK-1) rowg = TOK-1;
      gld_lds16(Xg + (size_t)rowg*DM + k0 + col, &lA[buf][qbase]);
      gld_lds16(Bsrc + (size_t)row*DM + k0 + col, &lB[buf][qbase]);
    }
  };

  stage(0, 0);
  __syncthreads();
  const int KT = DM / 32;
  for (int kt = 0; kt < KT; ++kt){
    int cur = kt & 1;
    if (kt + 1 < KT) stage(cur ^ 1, kt + 1);
    const u16* pa = &lA[cur][(wr*64 + (lane & 15))*32 + (lane >> 4)*8];
    const u16* pb = &lB[cur][(wc*64 + (lane & 15))*32 + (lane >> 4)*8];
    bf16x8 a[4], b[4];
#pragma unroll
    for (int m = 0; m < 4; ++m) a[m] = *(const bf16x8*)(pa + m*16*32);
#pragma unroll
    for (int n = 0; n < 4; ++n) b[n] = *(const bf16x8*)(pb + n*16*32);
#pragma unroll
    for (int m = 0; m < 4; ++m)
#pragma unroll
      for (int n = 0; n < 4; ++n)
        acc[m][n] = __builtin_amdgcn_mfma_f32_16x16x32_bf16(a[m], b[n], acc[m][n], 0, 0, 0);
    __syncthreads();
  }

#pragma unroll
  for (int n = 0; n < 4; ++n){
    int col = n0 + wc*64 + n*16 + (lane & 15);
    float bias = b1[(size_t)e*FF + col];
#pragma unroll
    for (int m = 0; m < 4; ++m){
      int rbase = wr*64 + m*16 + ((lane >> 4) << 2);
#pragma unroll
      for (int j = 0; j < 4; ++j){
        int rit = rbase + j;
        if (rit < valid){
          float v = acc[m][n][j] + bias;
          float g = 0.5f * v * (1.0f + erff(v * 0.70710678f));
          H[(size_t)(m0 + rit)*FF + col] = f2bf(g);
        }
      }
    }
  }
}

// ---- 9) grouped GEMM 2: out[tok] = H @ W2T^T + b2, fp32 scatter ----
__global__ __launch_bounds__(256) void k_ffn2(const u16* __restrict__ H,
    const u16* __restrict__ W2T, const float* __restrict__ b2,
    float* __restrict__ out, const int4* __restrict__ desc,
    const int* __restrict__ perm){
  int4 dd = desc[blockIdx.x];
  int e = dd.x; if (e < 0) return;
  int m0 = dd.y, valid = dd.z;
  int n0 = blockIdx.y * 128;
  __shared__ __align__(16) u16 lA[2][128*32];
  __shared__ __align__(16) u16 lB[2][128*32];
  int tid = threadIdx.x, lane = tid & 63, wave = tid >> 6;
  int wr = wave >> 1, wc = wave & 1;
  const u16* Bsrc = W2T + ((size_t)e*DM + n0)*FF;   // rows = d (n), k(f)-contig
  f32x4 acc[4][4] = {};

  auto stage = [&](int buf, int kt){
    int k0 = kt * 32;
#pragma unroll
    for (int i = 0; i < 2; ++i){
      int qbase = wave*512 + i*2048;
      int qe = qbase + lane*8;
      int row = qe >> 5, col = qe & 31;
      int rowg = m0 + row; if (rowg > TOK-1) rowg = TOK-1;
      gld_lds16(H + (size_t)rowg*FF + k0 + col, &lA[buf][qbase]);
      gld_lds16(Bsrc + (size_t)row*FF + k0 + col, &lB[buf][qbase]);
    }
  };

  stage(0, 0);
  __syncthreads();
  const int KT = FF / 32;
  for (int kt = 0; kt < KT; ++kt){
    int cur = kt & 1;
    if (kt + 1 < KT) stage(cur ^ 1, kt + 1);
    const u16* pa = &lA[cur][(wr*64 + (lane & 15))*32 + (lane >> 4)*8];
    const u16* pb = &lB[cur][(wc*64 + (lane & 15))*32 + (lane >> 4)*8];
    bf16x8 a[4], b[4];
#pragma unroll
    for (int m = 0; m < 4; ++m) a[m] = *(const bf16x8*)(pa + m*16*32);
#pragma unroll
    for (int n = 0; n < 4; ++n) b[n] = *(const bf16x8*)(pb + n*16*32);
#pragma unroll
    for (int m = 0; m < 4; ++m)
#pragma unroll
      for (int n = 0; n < 4; ++n)
        acc[m][n] = __builtin_amdgcn_mfma_f32_16x16x32_bf16(a[m], b[n], acc[m][n], 0, 0, 0);
    __syncthreads();
  }

#pragma unroll
  for (int m = 0; m < 4; ++m){
#pragma unroll
    for (int j = 0; j < 4; ++j){
      int rit = wr*64 + m*16 + ((lane >> 4) << 2) + j;
      if (rit < valid){
        int tok = perm[m0 + rit];
#pragma unroll
        for (int n = 0; n < 4; ++n){
          int col = n0 + wc*64 + n*16 + (lane & 15);
          out[(size_t)tok*DM + col] = acc[m][n][j] + b2[(size_t)e*DM + col];
        }
      }
    }
  }
}

extern "C" void kernel_launch(void* const* d_in, const int* in_sizes, int n_in,
                              void* d_out, int out_size, void* d_ws, size_t ws_size,
                              hipStream_t stream){
  const float* x   = (const float*)d_in[0];
  const float* gw  = (const float*)d_in[1];
  const float* gb  = (const float*)d_in[2];
  const float* W1  = (const float*)d_in[3];
  const float* b1  = (const float*)d_in[4];
  const float* W2  = (const float*)d_in[5];
  const float* b2  = (const float*)d_in[6];
  float* out = (float*)d_out;
  char* ws = (char*)d_ws;

  float* logits = (float*)(ws + O_LOGITS);
  float* mArr   = (float*)(ws + O_M);
  float* zArr   = (float*)(ws + O_Z);
  u32*   cnt    = (u32*)  (ws + O_CNT);
  u32*   cur    = (u32*)  (ws + O_CUR);
  int*   off    = (int*)  (ws + O_OFF);
  int4*  desc   = (int4*) (ws + O_DESC);
  int*   perm   = (int*)  (ws + O_PERM);
  int*   idx    = (int*)  (ws + O_IDX);
  u16*   Xg     = (u16*)  (ws + O_XG);
  u16*   W1T    = (u16*)  (ws + O_W1T);
  u16*   W2T    = (u16*)  (ws + O_W2T);
  u16*   Hbuf   = (u16*)  (ws + O_H);

  hipMemsetAsync(ws + O_CNT, 0, 128, stream);   // cnt + cur

  k_gate   <<<TOK/4, 256, 0, stream>>>(x, gw, gb, logits);
  k_lse    <<<32,    256, 0, stream>>>(logits, mArr, zArr);
  k_route  <<<TOK/256, 256, 0, stream>>>(logits, mArr, zArr, cnt, idx);
  k_plan   <<<1,     64,  0, stream>>>(cnt, off, desc, cur);
  k_scatter<<<TOK/256, 256, 0, stream>>>(idx, off, cur, perm);
  k_gather <<<TOK,   256, 0, stream>>>(x, perm, Xg);
  k_trans  <<<dim3(DM/64, FF/64, NE), 256, 0, stream>>>(W1, W1T, DM, FF);
  k_trans  <<<dim3(FF/64, DM/64, NE), 256, 0, stream>>>(W2, W2T, FF, DM);
  k_ffn1   <<<dim3(MAXT, FF/128), 256, 0, stream>>>(Xg, W1T, b1, Hbuf, desc);
  k_ffn2   <<<dim3(MAXT, DM/128), 256, 0, stream>>>(Hbuf, W2T, b2, out, desc, perm);
}

// Round 2
// 474.619 us; speedup vs baseline: 1.0559x; 1.0559x over previous
//
#include <hip/hip_runtime.h>
#include <hip/hip_bf16.h>

typedef unsigned short u16;
typedef unsigned int u32;

using bf16x8 = __attribute__((ext_vector_type(8))) short;
using f32x4  = __attribute__((ext_vector_type(4))) float;

static constexpr int TOK  = 8192;   // BS*L
static constexpr int SEQ  = 2048;
static constexpr int DM   = 1024;
static constexpr int FF   = 4096;
static constexpr int NE   = 8;
static constexpr int MAXT = 72;     // max M-tiles: 8192/128 + 8 remainders
static constexpr int NT1  = FF/128; // 32 N-tiles for ffn1
static constexpr int NT2  = DM/128; // 8  N-tiles for ffn2

// ---- workspace layout (bytes) ----
static constexpr size_t O_LOGITS = 0;                                  // 8192*8*4
static constexpr size_t O_M      = 262144;                            // 32 f32
static constexpr size_t O_Z      = O_M + 128;                         // 32 f32
static constexpr size_t O_CNT    = O_Z + 128;                         // 8 u32
static constexpr size_t O_CUR    = O_CNT + 64;                        // 8 u32
static constexpr size_t O_OFF    = O_CUR + 64;                        // 9 i32
static constexpr size_t O_DESC   = 263168;                            // 72 * int4
static constexpr size_t O_PERM   = 266240;                            // 8192 i32
static constexpr size_t O_IDX    = 299008;                            // 8192 i32
static constexpr size_t O_XG     = 524288;                            // 16 MB bf16
static constexpr size_t O_W1T    = O_XG  + (size_t)TOK*DM*2;          // 64 MB bf16 [e][f][d]
static constexpr size_t O_W2T    = O_W1T + (size_t)NE*DM*FF*2;        // 64 MB bf16 [e][d][f]
static constexpr size_t O_H      = O_W2T + (size_t)NE*DM*FF*2;        // 64 MB bf16 [pos][f]
// total ~218.6 MB

__device__ __forceinline__ u16 f2bf(float f){
  __hip_bfloat16 h = __float2bfloat16(f);
  return *reinterpret_cast<u16*>(&h);
}

__device__ __forceinline__ void gld_lds16(const void* g, void* l){
  __builtin_amdgcn_global_load_lds((const __attribute__((address_space(1))) void*)g,
                                   (__attribute__((address_space(3))) void*)l, 16, 0, 0);
}

// cheap GELU: tanh-form as v * sigmoid(2u), u = 0.7978845608*(v + 0.044715 v^3)
// gelu(v) = v / (1 + exp2(-2*log2(e)*u));  |err vs erf-form| < ~3e-3
__device__ __forceinline__ float gelu_f(float v){
  float u = v * fmaf(v*v, 0.044715f, 1.0f) * 0.7978845608f;
  float ex = __builtin_amdgcn_exp2f(u * -2.885390082f);   // exp(-2u)
  return v * __builtin_amdgcn_rcpf(1.0f + ex);
}

// ---- 1) gate logits: one wave per token, fp32, tree-reduced ----
__global__ void k_gate(const float* __restrict__ x, const float* __restrict__ gw,
                       const float* __restrict__ gb, float* __restrict__ logits){
  __shared__ float sgw[DM*NE];
  for (int i = threadIdx.x; i < DM*NE; i += 256) sgw[i] = gw[i];
  __syncthreads();
  int wave = threadIdx.x >> 6, lane = threadIdx.x & 63;
  int t = blockIdx.x * 4 + wave;
  const float* xr = x + (size_t)t * DM;
  float acc[NE];
#pragma unroll
  for (int e = 0; e < NE; ++e) acc[e] = 0.f;
#pragma unroll
  for (int k = 0; k < 16; ++k){
    int d = k*64 + lane;
    float xv = xr[d];
    const float* g = &sgw[d*NE];
#pragma unroll
    for (int e = 0; e < NE; ++e) acc[e] = fmaf(xv, g[e], acc[e]);
  }
#pragma unroll
  for (int off = 32; off; off >>= 1)
#pragma unroll
    for (int e = 0; e < NE; ++e) acc[e] += __shfl_xor(acc[e], off);
  if (lane == 0){
#pragma unroll
    for (int e = 0; e < NE; ++e) logits[(size_t)t*NE + e] = acc[e] + gb[e];
  }
}

// ---- 2) per (b,e): max and sum(exp) over seq ----
__global__ void k_lse(const float* __restrict__ logits, float* __restrict__ mOut,
                      float* __restrict__ zOut){
  int be = blockIdx.x;            // b*8+e
  int b = be >> 3, e = be & 7;
  const float* base = logits + ((size_t)b*SEQ)*NE + e;
  float m = -INFINITY;
  for (int l = threadIdx.x; l < SEQ; l += 256) m = fmaxf(m, base[(size_t)l*NE]);
  __shared__ float red[8];
#pragma unroll
  for (int off = 32; off; off >>= 1) m = fmaxf(m, __shfl_xor(m, off));
  if ((threadIdx.x & 63) == 0) red[threadIdx.x >> 6] = m;
  __syncthreads();
  m = fmaxf(fmaxf(red[0], red[1]), fmaxf(red[2], red[3]));
  float s = 0.f;
  for (int l = threadIdx.x; l < SEQ; l += 256) s += expf(base[(size_t)l*NE] - m);
#pragma unroll
  for (int off = 32; off; off >>= 1) s += __shfl_xor(s, off);
  if ((threadIdx.x & 63) == 0) red[4 + (threadIdx.x >> 6)] = s;
  __syncthreads();
  if (threadIdx.x == 0){ mOut[be] = m; zOut[be] = red[4]+red[5]+red[6]+red[7]; }
}

// ---- 3) route: argmax_e of softmax(dim=seq) prob, count per expert ----
__global__ void k_route(const float* __restrict__ logits, const float* __restrict__ m,
                        const float* __restrict__ z, u32* __restrict__ cnt,
                        int* __restrict__ idx){
  int t = blockIdx.x*256 + threadIdx.x;
  int b = t >> 11;
  const float* lr = logits + (size_t)t*NE;
  float best = -INFINITY; int be = 0;
#pragma unroll
  for (int e = 0; e < NE; ++e){
    float p = expf(lr[e] - m[b*NE + e]) / z[b*NE + e];
    if (p > best){ best = p; be = e; }
  }
  idx[t] = be;
  atomicAdd(&cnt[be], 1u);
}

// ---- 4) plan: prefix offsets + static tile descriptors ----
__global__ void k_plan(const u32* __restrict__ cnt, int* __restrict__ off,
                       int4* __restrict__ desc, u32* __restrict__ cur){
  if (threadIdx.x == 0){
    int offs[NE+1]; int o = 0;
    for (int e = 0; e < NE; ++e){ offs[e] = o; o += (int)cnt[e]; }
    offs[NE] = o;
    int nt = 0;
    for (int e = 0; e < NE; ++e){
      int c = (int)cnt[e];
      for (int s = 0; s < c; s += 128)
        desc[nt++] = make_int4(e, offs[e] + s, min(128, c - s), 0);
      off[e] = offs[e]; cur[e] = 0u;
    }
    off[NE] = offs[NE];
    for (int i = nt; i < MAXT; ++i) desc[i] = make_int4(-1, 0, 0, 0);
  }
}

// ---- 5) scatter token ids into expert-sorted perm ----
__global__ void k_scatter(const int* __restrict__ idx, const int* __restrict__ off,
                          u32* __restrict__ cur, int* __restrict__ perm){
  int t = blockIdx.x*256 + threadIdx.x;
  int e = idx[t];
  int pos = off[e] + (int)atomicAdd(&cur[e], 1u);
  perm[pos] = t;
}

// ---- 6) gather x rows in perm order, fp32 -> bf16 ----
__global__ void k_gather(const float* __restrict__ x, const int* __restrict__ perm,
                         u16* __restrict__ Xg){
  int p = blockIdx.x;
  int t = perm[p];
  const float4* src = (const float4*)(x + (size_t)t*DM);
  float4 v = src[threadIdx.x];
  uint2 o;
  o.x = (u32)f2bf(v.x) | ((u32)f2bf(v.y) << 16);
  o.y = (u32)f2bf(v.z) | ((u32)f2bf(v.w) << 16);
  *(uint2*)(Xg + (size_t)p*DM + threadIdx.x*4) = o;
}

// ---- 7) transpose + convert weights: in fp32 [E][R][C] -> out bf16 [E][C][R] ----
__global__ void k_trans(const float* __restrict__ in, u16* __restrict__ out,
                        int R, int C){
  __shared__ float tile[64][65];
  int e = blockIdx.z;
  int r0 = blockIdx.x*64, c0 = blockIdx.y*64;
  const float* src = in + ((size_t)e*R + r0)*C + c0;
  int lr = threadIdx.x >> 4, lc = (threadIdx.x & 15) * 4;
#pragma unroll
  for (int i = 0; i < 4; ++i){
    float4 v = *(const float4*)(src + (size_t)(lr + i*16)*C + lc);
    tile[lr + i*16][lc+0] = v.x; tile[lr + i*16][lc+1] = v.y;
    tile[lr + i*16][lc+2] = v.z; tile[lr + i*16][lc+3] = v.w;
  }
  __syncthreads();
  u16* dst = out + ((size_t)e*C + c0)*R + r0;
#pragma unroll
  for (int i = 0; i < 4; ++i){
    int oc = lr + i*16;          // output row = original column
    u16 a0 = f2bf(tile[lc+0][oc]);
    u16 a1 = f2bf(tile[lc+1][oc]);
    u16 a2 = f2bf(tile[lc+2][oc]);
    u16 a3 = f2bf(tile[lc+3][oc]);
    uint2 o; o.x = (u32)a0 | ((u32)a1 << 16); o.y = (u32)a2 | ((u32)a3 << 16);
    *(uint2*)(dst + (size_t)oc*R + lc) = o;
  }
}

// ---- 8) grouped GEMM 1: H = gelu(Xg @ W1T^T + b1), bf16 out ----
// m97 structure: 128x128 tile, BK=32, 4 waves (2x2), global_load_lds x16, dbuf LDS.
// 1D grid, m-fastest ordering (consecutive blocks share expert B-panel),
// bijective XCD-chunk swizzle (nwg % 8 == 0).
__global__ __launch_bounds__(256) void k_ffn1(const u16* __restrict__ Xg,
    const u16* __restrict__ W1T, const float* __restrict__ b1,
    u16* __restrict__ H, const int4* __restrict__ desc){
  int pid = blockIdx.x;                       // nwg = MAXT*NT1 = 2304, %8==0
  int pid_sw = (pid & 7) * (MAXT*NT1/8) + (pid >> 3);
  int mt = pid_sw % MAXT;
  int n0 = (pid_sw / MAXT) * 128;
  int4 dd = desc[mt];
  int e = dd.x; if (e < 0) return;
  int m0 = dd.y, valid = dd.z;
  __shared__ __align__(16) u16 lA[2][128*32];
  __shared__ __align__(16) u16 lB[2][128*32];
  int tid = threadIdx.x, lane = tid & 63, wave = tid >> 6;
  int wr = wave >> 1, wc = wave & 1;
  const u16* Bsrc = W1T + ((size_t)e*FF + n0)*DM;   // rows = f (n), k-contig
  f32x4 acc[4][4] = {};

  auto stage = [&](int buf, int kt){
    int k0 = kt * 32;
#pragma unroll
    for (int i = 0; i < 2; ++i){
      int qbase = wave*512 + i*2048;               // wave-uniform LDS elem base
      int qe = qbase + lane*8;
      int row = qe >> 5, col = qe & 31;
      int rowg = m0 + row; if (rowg > TOK-1) rowg = TOK-1;
      gld_lds16(Xg + (size_t)rowg*DM + k0 + col, &lA[buf][qbase]);
      gld_lds16(Bsrc + (size_t)row*DM + k0 + col, &lB[buf][qbase]);
    }
  };

  stage(0, 0);
  __syncthreads();
  const int KT = DM / 32;
  for (int kt = 0; kt < KT; ++kt){
    int cur = kt & 1;
    if (kt + 1 < KT) stage(cur ^ 1, kt + 1);
    const u16* pa = &lA[cur][(wr*64 + (lane & 15))*32 + (lane >> 4)*8];
    const u16* pb = &lB[cur][(wc*64 + (lane & 15))*32 + (lane >> 4)*8];
    bf16x8 a[4], b[4];
#pragma unroll
    for (int m = 0; m < 4; ++m) a[m] = *(const bf16x8*)(pa + m*16*32);
#pragma unroll
    for (int n = 0; n < 4; ++n) b[n] = *(const bf16x8*)(pb + n*16*32);
#pragma unroll
    for (int m = 0; m < 4; ++m)
#pragma unroll
      for (int n = 0; n < 4; ++n)
        acc[m][n] = __builtin_amdgcn_mfma_f32_16x16x32_bf16(a[m], b[n], acc[m][n], 0, 0, 0);
    __syncthreads();
  }

#pragma unroll
  for (int n = 0; n < 4; ++n){
    int col = n0 + wc*64 + n*16 + (lane & 15);
    float bias = b1[(size_t)e*FF + col];
#pragma unroll
    for (int m = 0; m < 4; ++m){
      int rbase = wr*64 + m*16 + ((lane >> 4) << 2);
#pragma unroll
      for (int j = 0; j < 4; ++j){
        int rit = rbase + j;
        if (rit < valid){
          float v = acc[m][n][j] + bias;
          H[(size_t)(m0 + rit)*FF + col] = f2bf(gelu_f(v));
        }
      }
    }
  }
}

// ---- 9) grouped GEMM 2: out[tok] = H @ W2T^T + b2, fp32 scatter ----
__global__ __launch_bounds__(256) void k_ffn2(const u16* __restrict__ H,
    const u16* __restrict__ W2T, const float* __restrict__ b2,
    float* __restrict__ out, const int4* __restrict__ desc,
    const int* __restrict__ perm){
  int pid = blockIdx.x;                       // nwg = MAXT*NT2 = 576, %8==0
  int pid_sw = (pid & 7) * (MAXT*NT2/8) + (pid >> 3);
  int mt = pid_sw % MAXT;
  int n0 = (pid_sw / MAXT) * 128;
  int4 dd = desc[mt];
  int e = dd.x; if (e < 0) return;
  int m0 = dd.y, valid = dd.z;
  __shared__ __align__(16) u16 lA[2][128*32];
  __shared__ __align__(16) u16 lB[2][128*32];
  int tid = threadIdx.x, lane = tid & 63, wave = tid >> 6;
  int wr = wave >> 1, wc = wave & 1;
  const u16* Bsrc = W2T + ((size_t)e*DM + n0)*FF;   // rows = d (n), k(f)-contig
  f32x4 acc[4][4] = {};

  auto stage = [&](int buf, int kt){
    int k0 = kt * 32;
#pragma unroll
    for (int i = 0; i < 2; ++i){
      int qbase = wave*512 + i*2048;
      int qe = qbase + lane*8;
      int row = qe >> 5, col = qe & 31;
      int rowg = m0 + row; if (rowg > TOK-1) rowg = TOK-1;
      gld_lds16(H + (size_t)rowg*FF + k0 + col, &lA[buf][qbase]);
      gld_lds16(Bsrc + (size_t)row*FF + k0 + col, &lB[buf][qbase]);
    }
  };

  stage(0, 0);
  __syncthreads();
  const int KT = FF / 32;
  for (int kt = 0; kt < KT; ++kt){
    int cur = kt & 1;
    if (kt + 1 < KT) stage(cur ^ 1, kt + 1);
    const u16* pa = &lA[cur][(wr*64 + (lane & 15))*32 + (lane >> 4)*8];
    const u16* pb = &lB[cur][(wc*64 + (lane & 15))*32 + (lane >> 4)*8];
    bf16x8 a[4], b[4];
#pragma unroll
    for (int m = 0; m < 4; ++m) a[m] = *(const bf16x8*)(pa + m*16*32);
#pragma unroll
    for (int n = 0; n < 4; ++n) b[n] = *(const bf16x8*)(pb + n*16*32);
#pragma unroll
    for (int m = 0; m < 4; ++m)
#pragma unroll
      for (int n = 0; n < 4; ++n)
        acc[m][n] = __builtin_amdgcn_mfma_f32_16x16x32_bf16(a[m], b[n], acc[m][n], 0, 0, 0);
    __syncthreads();
  }

#pragma unroll
  for (int m = 0; m < 4; ++m){
#pragma unroll
    for (int j = 0; j < 4; ++j){
      int rit = wr*64 + m*16 + ((lane >> 4) << 2) + j;
      if (rit < valid){
        int tok = perm[m0 + rit];
#pragma unroll
        for (int n = 0; n < 4; ++n){
          int col = n0 + wc*64 + n*16 + (lane & 15);
          out[(size_t)tok*DM + col] = acc[m][n][j] + b2[(size_t)e*DM + col];
        }
      }
    }
  }
}

extern "C" void kernel_launch(void* const* d_in, const int* in_sizes, int n_in,
                              void* d_out, int out_size, void* d_ws, size_t ws_size,
                              hipStream_t stream){
  const float* x   = (const float*)d_in[0];
  const float* gw  = (const float*)d_in[1];
  const float* gb  = (const float*)d_in[2];
  const float* W1  = (const float*)d_in[3];
  const float* b1  = (const float*)d_in[4];
  const float* W2  = (const float*)d_in[5];
  const float* b2  = (const float*)d_in[6];
  float* out = (float*)d_out;
  char* ws = (char*)d_ws;

  float* logits = (float*)(ws + O_LOGITS);
  float* mArr   = (float*)(ws + O_M);
  float* zArr   = (float*)(ws + O_Z);
  u32*   cnt    = (u32*)  (ws + O_CNT);
  u32*   cur    = (u32*)  (ws + O_CUR);
  int*   off    = (int*)  (ws + O_OFF);
  int4*  desc   = (int4*) (ws + O_DESC);
  int*   perm   = (int*)  (ws + O_PERM);
  int*   idx    = (int*)  (ws + O_IDX);
  u16*   Xg     = (u16*)  (ws + O_XG);
  u16*   W1T    = (u16*)  (ws + O_W1T);
  u16*   W2T    = (u16*)  (ws + O_W2T);
  u16*   Hbuf   = (u16*)  (ws + O_H);

  hipMemsetAsync(ws + O_CNT, 0, 128, stream);   // cnt + cur

  k_gate   <<<TOK/4, 256, 0, stream>>>(x, gw, gb, logits);
  k_lse    <<<32,    256, 0, stream>>>(logits, mArr, zArr);
  k_route  <<<TOK/256, 256, 0, stream>>>(logits, mArr, zArr, cnt, idx);
  k_plan   <<<1,     64,  0, stream>>>(cnt, off, desc, cur);
  k_scatter<<<TOK/256, 256, 0, stream>>>(idx, off, cur, perm);
  k_gather <<<TOK,   256, 0, stream>>>(x, perm, Xg);
  k_trans  <<<dim3(DM/64, FF/64, NE), 256, 0, stream>>>(W1, W1T, DM, FF);
  k_trans  <<<dim3(FF/64, DM/64, NE), 256, 0, stream>>>(W2, W2T, FF, DM);
  k_ffn1   <<<MAXT*NT1, 256, 0, stream>>>(Xg, W1T, b1, Hbuf, desc);
  k_ffn2   <<<MAXT*NT2, 256, 0, stream>>>(Hbuf, W2T, b2, out, desc, perm);
}